// Round 5
// baseline (417.683 us; speedup 1.0000x reference)
//
#include <hip/hip_runtime.h>
#include <math.h>

// Problem constants
#define TB 2
#define TT 31
#define TH 160
#define TW 160
#define THW (TH*TW)            // 25600
#define NPER (TB*TT*THW)       // 1,587,200
#define HCN 16
#define TCH 4                  // t-chunk for k4 (small -> big grid for latency hiding)
#define LS 24                  // LDS row stride (18 used) -> 2-way banking on reads

// Workspace layout (floats)
#define H_ELEMS (TB*HCN*TT*THW)
#define C2_OFF  H_ELEMS
#define C3_OFF  (C2_OFF + NPER)
#define S1_OFF  (C3_OFF + NPER)
#define AB1_OFF (S1_OFF + 64)
#define S2_OFF  (AB1_OFF + 64)
#define AB2_OFF (S2_OFF + 4)

__device__ __forceinline__ float sigmoidf_(float x) {
    return __builtin_amdgcn_rcpf(1.f + __expf(-x));
}
__device__ __forceinline__ float tanhf_(float x) {
    return 2.f * __builtin_amdgcn_rcpf(1.f + __expf(-2.f * x)) - 1.f;
}

// ---------- kernel 1: conv1 per-channel sum/sumsq, 4 channels per block ----------
// grid: (8 cgroups, 100 tiles, 2 b), block 256 = 16x16
__global__ __launch_bounds__(256)
void k1_gates_stats(const float* __restrict__ in, const float* __restrict__ wg,
                    float* __restrict__ stats) {
    __shared__ float pl[18*LS];
    int c0 = blockIdx.x * 4, tile = blockIdx.y, b = blockIdx.z;
    int ty0 = (tile / 10) * 16, tx0 = (tile % 10) * 16;
    int tid = threadIdx.x;
    int ly = tid >> 4, lx = tid & 15;

    float w[4][27];
    #pragma unroll
    for (int ch = 0; ch < 4; ++ch)
        #pragma unroll
        for (int i = 0; i < 27; ++i) w[ch][i] = wg[(c0 + ch)*27 + i];

    int i0 = tid, i1 = tid + 256;
    int py0 = i0 / 18, px0 = i0 % 18;
    int py1 = i1 / 18, px1 = i1 % 18;
    int gy0 = ty0 + py0 - 1, gx0 = tx0 + px0 - 1;
    int gy1 = ty0 + py1 - 1, gx1 = tx0 + px1 - 1;
    bool ok0 = (gy0 >= 0 && gy0 < TH && gx0 >= 0 && gx0 < TW);
    bool ok1 = (i1 < 324) && (gy1 >= 0 && gy1 < TH && gx1 >= 0 && gx1 < TW);
    long off0 = (long)gy0 * TW + gx0;
    long off1 = (long)gy1 * TW + gx1;

    float pm[9], pc_[9], pn[9];
    #pragma unroll
    for (int i = 0; i < 9; ++i) pm[i] = 0.f;

    {
        long base = (long)(b*TT + 0) * THW;
        float r0 = ok0 ? in[base + off0] : 0.f;
        float r1 = ok1 ? in[base + off1] : 0.f;
        pl[py0*LS + px0] = r0;
        if (i1 < 324) pl[py1*LS + px1] = r1;
        __syncthreads();
        #pragma unroll
        for (int ky = 0; ky < 3; ++ky)
            #pragma unroll
            for (int kx = 0; kx < 3; ++kx)
                pc_[ky*3 + kx] = pl[(ly + ky)*LS + (lx + kx)];
    }
    float r0, r1;
    {
        long base = (long)(b*TT + 1) * THW;
        r0 = ok0 ? in[base + off0] : 0.f;
        r1 = ok1 ? in[base + off1] : 0.f;
    }

    float s[4] = {0.f,0.f,0.f,0.f}, q[4] = {0.f,0.f,0.f,0.f};
    for (int t = 0; t < TT; ++t) {
        __syncthreads();
        pl[py0*LS + px0] = r0;
        if (i1 < 324) pl[py1*LS + px1] = r1;
        if (t + 2 <= TT - 1) {
            long base = (long)(b*TT + t + 2) * THW;
            r0 = ok0 ? in[base + off0] : 0.f;
            r1 = ok1 ? in[base + off1] : 0.f;
        } else { r0 = 0.f; r1 = 0.f; }
        __syncthreads();
        #pragma unroll
        for (int ky = 0; ky < 3; ++ky)
            #pragma unroll
            for (int kx = 0; kx < 3; ++kx)
                pn[ky*3 + kx] = pl[(ly + ky)*LS + (lx + kx)];

        #pragma unroll
        for (int ch = 0; ch < 4; ++ch) {
            float v = 0.f;
            #pragma unroll
            for (int i = 0; i < 9; ++i) v = fmaf(w[ch][i],      pm[i], v);
            #pragma unroll
            for (int i = 0; i < 9; ++i) v = fmaf(w[ch][9 + i],  pc_[i], v);
            #pragma unroll
            for (int i = 0; i < 9; ++i) v = fmaf(w[ch][18 + i], pn[i], v);
            s[ch] += v; q[ch] += v*v;
        }
        #pragma unroll
        for (int i = 0; i < 9; ++i) { pm[i] = pc_[i]; pc_[i] = pn[i]; }
    }

    #pragma unroll
    for (int ch = 0; ch < 4; ++ch) {
        #pragma unroll
        for (int off = 32; off > 0; off >>= 1) {
            s[ch] += __shfl_down(s[ch], off, 64);
            q[ch] += __shfl_down(q[ch], off, 64);
        }
    }
    __shared__ float red[4][8];
    int lane = tid & 63, wid = tid >> 6;
    if (lane == 0) {
        #pragma unroll
        for (int ch = 0; ch < 4; ++ch) { red[wid][ch] = s[ch]; red[wid][4 + ch] = q[ch]; }
    }
    __syncthreads();
    if (tid == 0) {
        #pragma unroll
        for (int ch = 0; ch < 4; ++ch) {
            atomicAdd(&stats[c0 + ch],      red[0][ch] + red[1][ch] + red[2][ch] + red[3][ch]);
            atomicAdd(&stats[32 + c0 + ch], red[0][4+ch] + red[1][4+ch] + red[2][4+ch] + red[3][4+ch]);
        }
    }
}

// ---------- kernel 2: finalize gate BN params ----------
__global__ void k2_fin1(const float* __restrict__ stats, const float* __restrict__ gamma,
                        const float* __restrict__ beta, float* __restrict__ ab) {
    int c = threadIdx.x;
    if (c < 32) {
        float n = (float)NPER;
        float mean = stats[c] / n;
        float var  = stats[32 + c] / n - mean*mean;
        float a = gamma[c] * rsqrtf(var + 1e-5f);
        ab[c]      = a;
        ab[32 + c] = beta[c] - mean * a;
    }
}

// ---------- kernel 3: conv1 recompute + BN + act + scan, 2 channels per block ----------
// grid: (8 cgroups, 100 tiles, 2 b), block 256 = 16x16
__global__ __launch_bounds__(256)
void k3_scan(const float* __restrict__ in, const float* __restrict__ wg,
             const float* __restrict__ ab, const int* __restrict__ rev_p,
             float* __restrict__ hbuf) {
    __shared__ float pl[18*LS];
    int c0 = blockIdx.x * 2, tile = blockIdx.y, b = blockIdx.z;
    int ty0 = (tile / 10) * 16, tx0 = (tile % 10) * 16;
    int tid = threadIdx.x;
    int ly = tid >> 4, lx = tid & 15;
    int y = ty0 + ly, x = tx0 + lx;

    float wz[2][27], wf[2][27];
    #pragma unroll
    for (int ch = 0; ch < 2; ++ch)
        #pragma unroll
        for (int i = 0; i < 27; ++i) {
            wz[ch][i] = wg[(c0 + ch)*27 + i];
            wf[ch][i] = wg[(c0 + ch + 16)*27 + i];
        }
    float az[2], bz[2], af[2], bf[2];
    #pragma unroll
    for (int ch = 0; ch < 2; ++ch) {
        az[ch] = ab[c0 + ch];      bz[ch] = ab[32 + c0 + ch];
        af[ch] = ab[c0 + ch + 16]; bf[ch] = ab[32 + c0 + ch + 16];
    }
    int rev = rev_p[0];

    int i0 = tid, i1 = tid + 256;
    int py0 = i0 / 18, px0 = i0 % 18;
    int py1 = i1 / 18, px1 = i1 % 18;
    int gy0 = ty0 + py0 - 1, gx0 = tx0 + px0 - 1;
    int gy1 = ty0 + py1 - 1, gx1 = tx0 + px1 - 1;
    bool ok0 = (gy0 >= 0 && gy0 < TH && gx0 >= 0 && gx0 < TW);
    bool ok1 = (i1 < 324) && (gy1 >= 0 && gy1 < TH && gx1 >= 0 && gx1 < TW);
    long off0 = (long)gy0 * TW + gx0;
    long off1 = (long)gy1 * TW + gx1;

    float h[2] = {0.f, 0.f};
    float pm[9], pc_[9], pn[9];
    long hb0 = ((long)(b*HCN + c0))     * TT * THW + (long)y*TW + x;
    long hb1 = ((long)(b*HCN + c0 + 1)) * TT * THW + (long)y*TW + x;

#define K3_STEP(FRESH)                                                          \
    {                                                                           \
        __syncthreads();                                                        \
        pl[py0*LS + px0] = r0;                                                  \
        if (i1 < 324) pl[py1*LS + px1] = r1;                                    \
        if (tnext >= 0 && tnext < TT) {                                         \
            long base = (long)(b*TT + tnext) * THW;                             \
            r0 = ok0 ? in[base + off0] : 0.f;                                   \
            r1 = ok1 ? in[base + off1] : 0.f;                                   \
        } else { r0 = 0.f; r1 = 0.f; }                                          \
        __syncthreads();                                                        \
        _Pragma("unroll")                                                       \
        for (int ky = 0; ky < 3; ++ky)                                          \
            _Pragma("unroll")                                                   \
            for (int kx = 0; kx < 3; ++kx)                                      \
                FRESH[ky*3 + kx] = pl[(ly + ky)*LS + (lx + kx)];                \
        _Pragma("unroll")                                                       \
        for (int ch = 0; ch < 2; ++ch) {                                        \
            float vz = 0.f, vf = 0.f;                                           \
            _Pragma("unroll")                                                   \
            for (int i = 0; i < 9; ++i) { vz = fmaf(wz[ch][i],      pm[i], vz);  vf = fmaf(wf[ch][i],      pm[i], vf); } \
            _Pragma("unroll")                                                   \
            for (int i = 0; i < 9; ++i) { vz = fmaf(wz[ch][9 + i],  pc_[i], vz); vf = fmaf(wf[ch][9 + i],  pc_[i], vf); } \
            _Pragma("unroll")                                                   \
            for (int i = 0; i < 9; ++i) { vz = fmaf(wz[ch][18 + i], pn[i], vz);  vf = fmaf(wf[ch][18 + i], pn[i], vf); } \
            float z = tanhf_(fmaf(az[ch], vz, bz[ch]));                         \
            float f = sigmoidf_(fmaf(af[ch], vf, bf[ch]));                      \
            h[ch] = f*h[ch] + (1.f - f)*z;                                      \
        }                                                                       \
        hbuf[hb0 + (long)t * THW] = h[0];                                       \
        hbuf[hb1 + (long)t * THW] = h[1];                                       \
    }

    if (!rev) {
        #pragma unroll
        for (int i = 0; i < 9; ++i) pm[i] = 0.f;
        {
            long base = (long)(b*TT + 0) * THW;
            float s0 = ok0 ? in[base + off0] : 0.f;
            float s1 = ok1 ? in[base + off1] : 0.f;
            pl[py0*LS + px0] = s0;
            if (i1 < 324) pl[py1*LS + px1] = s1;
            __syncthreads();
            #pragma unroll
            for (int ky = 0; ky < 3; ++ky)
                #pragma unroll
                for (int kx = 0; kx < 3; ++kx)
                    pc_[ky*3 + kx] = pl[(ly + ky)*LS + (lx + kx)];
        }
        float r0, r1;
        {
            long base = (long)(b*TT + 1) * THW;
            r0 = ok0 ? in[base + off0] : 0.f;
            r1 = ok1 ? in[base + off1] : 0.f;
        }
        for (int t = 0; t < TT; ++t) {
            int tnext = t + 2;
            K3_STEP(pn)
            #pragma unroll
            for (int i = 0; i < 9; ++i) { pm[i] = pc_[i]; pc_[i] = pn[i]; }
        }
    } else {
        #pragma unroll
        for (int i = 0; i < 9; ++i) pn[i] = 0.f;
        {
            long base = (long)(b*TT + (TT - 1)) * THW;
            float s0 = ok0 ? in[base + off0] : 0.f;
            float s1 = ok1 ? in[base + off1] : 0.f;
            pl[py0*LS + px0] = s0;
            if (i1 < 324) pl[py1*LS + px1] = s1;
            __syncthreads();
            #pragma unroll
            for (int ky = 0; ky < 3; ++ky)
                #pragma unroll
                for (int kx = 0; kx < 3; ++kx)
                    pc_[ky*3 + kx] = pl[(ly + ky)*LS + (lx + kx)];
        }
        float r0, r1;
        {
            long base = (long)(b*TT + (TT - 2)) * THW;
            r0 = ok0 ? in[base + off0] : 0.f;
            r1 = ok1 ? in[base + off1] : 0.f;
        }
        for (int t = TT - 1; t >= 0; --t) {
            int tnext = t - 2;
            K3_STEP(pm)
            #pragma unroll
            for (int i = 0; i < 9; ++i) { pn[i] = pc_[i]; pc_[i] = pm[i]; }
        }
    }
#undef K3_STEP
}

// ---------- kernel 4: LDS-tiled conv2+conv3, 2-plane staging + reg prefetch ----------
// grid: (100 tiles, 8 t-chunks, 2 b), block 256 = 16x16
__global__ __launch_bounds__(256)
void k4_conv23(const float* __restrict__ hbuf, const float* __restrict__ wsc,
               const float* __restrict__ wsh, float* __restrict__ c2,
               float* __restrict__ c3, float* __restrict__ stats2) {
    __shared__ float pl2[18*LS];
    __shared__ float pl3[18*LS];

    int b  = blockIdx.z;
    int t0 = blockIdx.y * TCH;
    int t1 = min(t0 + TCH - 1, TT - 1);
    int tile = blockIdx.x;
    int ty0 = (tile / 10) * 16, tx0 = (tile % 10) * 16;
    int tid = threadIdx.x;
    int ly = tid >> 4, lx = tid & 15;
    int y = ty0 + ly, x = tx0 + lx;

    int ts = max(t0 - 1, 0), te = min(t1 + 1, TT - 1);
    int nplanes = (te - ts + 1) * 8;

    int i0 = tid, i1 = tid + 256;
    int py0 = i0 / 18, px0 = i0 % 18;
    int py1 = i1 / 18, px1 = i1 % 18;
    int gy0 = ty0 + py0 - 1, gx0 = tx0 + px0 - 1;
    int gy1 = ty0 + py1 - 1, gx1 = tx0 + px1 - 1;
    bool ok0 = (gy0 >= 0 && gy0 < TH && gx0 >= 0 && gx0 < TW);
    bool ok1 = (i1 < 324) && (gy1 >= 0 && gy1 < TH && gx1 >= 0 && gx1 < TW);
    long off0 = (long)gy0 * TW + gx0;
    long off1 = (long)gy1 * TW + gx1;

    float accP2 = 0.f, accC2 = 0.f, accN2 = 0.f;
    float accP3 = 0.f, accC3 = 0.f, accN3 = 0.f;
    float s2l = 0.f, q2l = 0.f, s3l = 0.f, q3l = 0.f;

    // prefetch plane 0
    float r2a, r2b, r3a, r3b;
    {
        long b2 = ((long)((b*HCN + 0)*TT + ts)) * THW;
        long b3 = ((long)((b*HCN + 8)*TT + ts)) * THW;
        r2a = ok0 ? hbuf[b2 + off0] : 0.f;
        r2b = ok1 ? hbuf[b2 + off1] : 0.f;
        r3a = ok0 ? hbuf[b3 + off0] : 0.f;
        r3b = ok1 ? hbuf[b3 + off1] : 0.f;
    }

    for (int p = 0; p < nplanes; ++p) {
        int c = p & 7;
        int t_in = ts + (p >> 3);
        __syncthreads();
        pl2[py0*LS + px0] = r2a;
        if (i1 < 324) pl2[py1*LS + px1] = r2b;
        pl3[py0*LS + px0] = r3a;
        if (i1 < 324) pl3[py1*LS + px1] = r3b;
        if (p + 1 < nplanes) {
            int cn = (p + 1) & 7, tn = ts + ((p + 1) >> 3);
            long b2 = ((long)((b*HCN + cn)*TT + tn)) * THW;
            long b3 = ((long)((b*HCN + 8 + cn)*TT + tn)) * THW;
            r2a = ok0 ? hbuf[b2 + off0] : 0.f;
            r2b = ok1 ? hbuf[b2 + off1] : 0.f;
            r3a = ok0 ? hbuf[b3 + off0] : 0.f;
            r3b = ok1 ? hbuf[b3 + off1] : 0.f;
        }
        __syncthreads();

        float t2[9], t3[9];
        #pragma unroll
        for (int ky = 0; ky < 3; ++ky)
            #pragma unroll
            for (int kx = 0; kx < 3; ++kx) {
                int li = (ly + ky)*LS + (lx + kx);
                t2[ky*3 + kx] = pl2[li];
                t3[ky*3 + kx] = pl3[li];
            }
        const float* w2 = wsc + c*27;
        const float* w3 = wsh + c*27;
        #pragma unroll
        for (int i = 0; i < 9; ++i) {
            accN2 = fmaf(w2[i],      t2[i], accN2);
            accC2 = fmaf(w2[9 + i],  t2[i], accC2);
            accP2 = fmaf(w2[18 + i], t2[i], accP2);
            accN3 = fmaf(w3[i],      t3[i], accN3);
            accC3 = fmaf(w3[9 + i],  t3[i], accC3);
            accP3 = fmaf(w3[18 + i], t3[i], accP3);
        }

        if (c == 7) {
            int t_out = t_in - 1;
            if (t_out >= t0 && t_out <= t1) {
                long oidx = ((long)(b*TT + t_out)) * THW + (long)y*TW + x;
                c2[oidx] = accP2; c3[oidx] = accP3;
                s2l += accP2; q2l += accP2*accP2;
                s3l += accP3; q3l += accP3*accP3;
            }
            accP2 = accC2; accC2 = accN2; accN2 = 0.f;
            accP3 = accC3; accC3 = accN3; accN3 = 0.f;
        }
    }
    if (t1 == TT - 1) {
        long oidx = ((long)(b*TT + (TT - 1))) * THW + (long)y*TW + x;
        c2[oidx] = accP2; c3[oidx] = accP3;
        s2l += accP2; q2l += accP2*accP2;
        s3l += accP3; q3l += accP3*accP3;
    }

    #pragma unroll
    for (int off = 32; off > 0; off >>= 1) {
        s2l += __shfl_down(s2l, off, 64);
        q2l += __shfl_down(q2l, off, 64);
        s3l += __shfl_down(s3l, off, 64);
        q3l += __shfl_down(q3l, off, 64);
    }
    __shared__ float red[4][4];
    int lane = tid & 63, wid = tid >> 6;
    __syncthreads();
    if (lane == 0) { red[0][wid] = s2l; red[1][wid] = q2l; red[2][wid] = s3l; red[3][wid] = q3l; }
    __syncthreads();
    if (tid == 0) {
        #pragma unroll
        for (int j = 0; j < 4; ++j)
            atomicAdd(&stats2[j], red[j][0] + red[j][1] + red[j][2] + red[j][3]);
    }
}

// ---------- kernel 5: finalize scale/shift BN params ----------
__global__ void k5_fin2(const float* __restrict__ stats2,
                        const float* __restrict__ gs, const float* __restrict__ bs,
                        const float* __restrict__ gt, const float* __restrict__ bt,
                        float* __restrict__ ab2) {
    if (threadIdx.x == 0) {
        float n = (float)NPER;
        float m2 = stats2[0] / n, v2 = stats2[1] / n - m2*m2;
        float a2 = gs[0] * rsqrtf(v2 + 1e-5f);
        ab2[0] = a2; ab2[1] = bs[0] - m2*a2;
        float m3 = stats2[2] / n, v3 = stats2[3] / n - m3*m3;
        float a3 = gt[0] * rsqrtf(v3 + 1e-5f);
        ab2[2] = a3; ab2[3] = bt[0] - m3*a3;
    }
}

// ---------- kernel 6: epilogue, float4 ----------
__global__ __launch_bounds__(256)
void k6_final(const float4* __restrict__ c2, const float4* __restrict__ c3,
              const float* __restrict__ ab2, float4* __restrict__ out) {
    int i = blockIdx.x * blockDim.x + threadIdx.x;
    if (i < NPER/4) {
        float a2 = ab2[0], b2 = ab2[1], a3 = ab2[2], b3 = ab2[3];
        float4 v2 = c2[i], v3 = c3[i];
        float4 sc, sh;
        sc.x = sigmoidf_(fmaf(a2, v2.x, b2) + 2.f) + 1e-4f;
        sc.y = sigmoidf_(fmaf(a2, v2.y, b2) + 2.f) + 1e-4f;
        sc.z = sigmoidf_(fmaf(a2, v2.z, b2) + 2.f) + 1e-4f;
        sc.w = sigmoidf_(fmaf(a2, v2.w, b2) + 2.f) + 1e-4f;
        sh.x = fmaf(a3, v3.x, b3);
        sh.y = fmaf(a3, v3.y, b3);
        sh.z = fmaf(a3, v3.z, b3);
        sh.w = fmaf(a3, v3.w, b3);
        out[i] = sc;
        out[NPER/4 + i] = sh;
    }
}

// ---------- launch ----------
extern "C" void kernel_launch(void* const* d_in, const int* in_sizes, int n_in,
                              void* d_out, int out_size, void* d_ws, size_t ws_size,
                              hipStream_t stream) {
    const float* in          = (const float*)d_in[0];
    const float* w_gate      = (const float*)d_in[1];
    const float* gamma_gate  = (const float*)d_in[2];
    const float* beta_gate   = (const float*)d_in[3];
    const float* w_scale     = (const float*)d_in[4];
    const float* gamma_scale = (const float*)d_in[5];
    const float* beta_scale  = (const float*)d_in[6];
    const float* w_shift     = (const float*)d_in[7];
    const float* gamma_shift = (const float*)d_in[8];
    const float* beta_shift  = (const float*)d_in[9];
    const int*   rev         = (const int*)d_in[10];

    float* ws   = (float*)d_ws;
    float* hbuf = ws;
    float* c2   = ws + C2_OFF;
    float* c3   = ws + C3_OFF;
    float* s1   = ws + S1_OFF;
    float* ab1  = ws + AB1_OFF;
    float* s2   = ws + S2_OFF;
    float* ab2  = ws + AB2_OFF;
    float* out  = (float*)d_out;

    hipMemsetAsync(s1, 0, (64 + 64 + 4 + 4) * sizeof(float), stream);

    k1_gates_stats<<<dim3(8, 100, TB), 256, 0, stream>>>(in, w_gate, s1);
    k2_fin1<<<1, 32, 0, stream>>>(s1, gamma_gate, beta_gate, ab1);
    k3_scan<<<dim3(8, 100, TB), 256, 0, stream>>>(in, w_gate, ab1, rev, hbuf);
    k4_conv23<<<dim3(100, (TT + TCH - 1)/TCH, TB), 256, 0, stream>>>(hbuf, w_scale, w_shift, c2, c3, s2);
    k5_fin2<<<1, 64, 0, stream>>>(s2, gamma_scale, beta_scale, gamma_shift, beta_shift, ab2);
    k6_final<<<(NPER/4 + 255)/256, 256, 0, stream>>>((const float4*)c2, (const float4*)c3, ab2, (float4*)out);
}

// Round 6
// 263.188 us; speedup vs baseline: 1.5870x; 1.5870x over previous
//
#include <hip/hip_runtime.h>
#include <math.h>

// Problem constants
#define TB 2
#define TT 31
#define TH 160
#define TW 160
#define THW (TH*TW)            // 25600
#define NPER (TB*TT*THW)       // 1,587,200
#define HCN 16
#define TCH 8                  // t-chunk for k4 (best measured)
#define LSK 40                 // LDS row stride for 34-wide halo rows (2-way banking)

// Workspace layout (bytes). gates bf16: z-half [0,50.79MB), f-half [50.79,101.58MB).
// After k3, z-half is overwritten in-place with h (bf16). c2/c3 fp32 alias the
// (dead) f-half. Stats at the end. Total ~101.6MB (< proven-safe 114.5MB).
#define GF_OFF_US  25395200L    // ushort offset of f-gates (2*16*31*25600)
#define C2_BYTE    50790400L    // byte offset of c2 (aliases f-gates, dead by then)
#define STATS_BYTE 101580800L

__device__ __forceinline__ float sigmoidf_(float x) {
    return __builtin_amdgcn_rcpf(1.f + __expf(-x));
}
__device__ __forceinline__ float tanhf_(float x) {
    return 2.f * __builtin_amdgcn_rcpf(1.f + __expf(-2.f * x)) - 1.f;
}
__device__ __forceinline__ unsigned short f2bf(float v) {
    unsigned int b = __float_as_uint(v);
    unsigned int r = (b + 0x7FFFu + ((b >> 16) & 1u)) >> 16;   // RNE
    return (unsigned short)r;
}
__device__ __forceinline__ float b2f(unsigned short u) {
    return __uint_as_float(((unsigned int)u) << 16);
}

// ---------- kernel 1: conv1 (all taps from LDS, no mid-loop barriers),
//            per-channel sum/sumsq + bf16 gate store ----------
// grid: (8 = chalf*4 + tchunk, 100 tiles, 2 b), block 256 = 32x8 tile
__global__ __launch_bounds__(256)
void k1_gates_stats(const float* __restrict__ in, const float* __restrict__ wg,
                    unsigned short* __restrict__ gout, float* __restrict__ stats) {
    __shared__ float pl[10*10*LSK];          // 10 t-planes, 10 rows x 40 (34 used)
    __shared__ float redS[4][16], redQ[4][16];

    int bx = blockIdx.x;
    int tc = bx & 3, chalf = bx >> 2;
    int tile = blockIdx.y, b = blockIdx.z;
    int ty0 = (tile / 5) * 8, tx0 = (tile % 5) * 32;
    int tid = threadIdx.x;
    int lyk = tid >> 5, lxk = tid & 31;
    int t0 = tc * 8;

    // stage 10 halo planes (t0-1 .. t0+8), 10x34 each, zero-padded
    for (int i = tid; i < 3400; i += 256) {
        int j = i / 340, pos = i - j*340;
        int py = pos / 34, px = pos - py*34;
        int t = t0 - 1 + j;
        int gy = ty0 - 1 + py, gx = tx0 - 1 + px;
        float v = 0.f;
        if (t >= 0 && t < TT && gy >= 0 && gy < TH && gx >= 0 && gx < TW)
            v = in[((long)(b*TT + t))*THW + gy*TW + gx];
        pl[j*(10*LSK) + py*LSK + px] = v;
    }
    __syncthreads();

    int c0 = chalf * 16;
    long gbase = chalf ? GF_OFF_US : 0L;
    int y = ty0 + lyk, x = tx0 + lxk;
    int hw = y*TW + x;

    float s[16], q[16];
    #pragma unroll
    for (int c = 0; c < 16; ++c) { s[c] = 0.f; q[c] = 0.f; }

    for (int j = 1; j <= 8; ++j) {
        int t = t0 - 1 + j;
        if (t >= TT) break;                  // uniform
        float tap[27];
        #pragma unroll
        for (int kt = 0; kt < 3; ++kt)
            #pragma unroll
            for (int ky = 0; ky < 3; ++ky)
                #pragma unroll
                for (int kx = 0; kx < 3; ++kx)
                    tap[kt*9 + ky*3 + kx] =
                        pl[(j-1+kt)*(10*LSK) + (lyk+ky)*LSK + (lxk+kx)];
        #pragma unroll
        for (int c = 0; c < 16; ++c) {
            const float* w = wg + (c0 + c)*27;
            float v = 0.f;
            #pragma unroll
            for (int i = 0; i < 27; ++i) v = fmaf(w[i], tap[i], v);
            s[c] += v; q[c] += v*v;
            gout[gbase + ((long)((b*HCN + c)*TT + t))*THW + hw] = f2bf(v);
        }
    }

    // block reduce 16 channels x (sum, sumsq)
    int lane = tid & 63, wid = tid >> 6;
    #pragma unroll
    for (int c = 0; c < 16; ++c) {
        float ss = s[c], qq = q[c];
        #pragma unroll
        for (int off = 32; off > 0; off >>= 1) {
            ss += __shfl_down(ss, off, 64);
            qq += __shfl_down(qq, off, 64);
        }
        if (lane == 0) { redS[wid][c] = ss; redQ[wid][c] = qq; }
    }
    __syncthreads();
    if (tid < 16) {
        int ch = c0 + tid;
        float ss = redS[0][tid] + redS[1][tid] + redS[2][tid] + redS[3][tid];
        float qq = redQ[0][tid] + redQ[1][tid] + redQ[2][tid] + redQ[3][tid];
        atomicAdd(&stats[ch], ss);
        atomicAdd(&stats[32 + ch], qq);
    }
}

// ---------- kernel 2: finalize gate BN params ----------
__global__ void k2_fin1(const float* __restrict__ stats, const float* __restrict__ gamma,
                        const float* __restrict__ beta, float* __restrict__ ab) {
    int c = threadIdx.x;
    if (c < 32) {
        float n = (float)NPER;
        float mean = stats[c] / n;
        float var  = stats[32 + c] / n - mean*mean;
        float a = gamma[c] * rsqrtf(var + 1e-5f);
        ab[c]      = a;
        ab[32 + c] = beta[c] - mean * a;
    }
}

// ---------- kernel 3: pointwise BN + act + scan (bf16 in, bf16 h in-place) ----------
// grid: (25, 16 ch, 2 b), block 256; each thread: 4 consecutive hw elems, scans t
__global__ __launch_bounds__(256)
void k3_scan(unsigned short* __restrict__ g, const float* __restrict__ ab,
             const int* __restrict__ rev_p) {
    int c = blockIdx.y, b = blockIdx.z;
    int p4 = blockIdx.x * blockDim.x + threadIdx.x;    // ushort4 index in plane
    float az = ab[c],      bz = ab[32 + c];
    float af = ab[16 + c], bf = ab[48 + c];
    int rev = rev_p[0];

    ushort4* g4 = (ushort4*)g;
    long zb = ((long)((b*HCN + c)*TT)) * (THW/4) + p4;
    long fb = zb + GF_OFF_US/4;

    float h0 = 0.f, h1 = 0.f, h2 = 0.f, h3 = 0.f;

#define K3_STEP(t)                                                        \
    {                                                                     \
        long o = (long)(t) * (THW/4);                                     \
        ushort4 zu = g4[zb + o];                                          \
        ushort4 fu = g4[fb + o];                                          \
        float z0 = tanhf_(fmaf(az, b2f(zu.x), bz));                       \
        float z1 = tanhf_(fmaf(az, b2f(zu.y), bz));                       \
        float z2 = tanhf_(fmaf(az, b2f(zu.z), bz));                       \
        float z3 = tanhf_(fmaf(az, b2f(zu.w), bz));                       \
        float f0 = sigmoidf_(fmaf(af, b2f(fu.x), bf));                    \
        float f1 = sigmoidf_(fmaf(af, b2f(fu.y), bf));                    \
        float f2 = sigmoidf_(fmaf(af, b2f(fu.z), bf));                    \
        float f3 = sigmoidf_(fmaf(af, b2f(fu.w), bf));                    \
        h0 = f0*h0 + (1.f - f0)*z0;                                       \
        h1 = f1*h1 + (1.f - f1)*z1;                                       \
        h2 = f2*h2 + (1.f - f2)*z2;                                       \
        h3 = f3*h3 + (1.f - f3)*z3;                                       \
        ushort4 hu;                                                       \
        hu.x = f2bf(h0); hu.y = f2bf(h1); hu.z = f2bf(h2); hu.w = f2bf(h3); \
        g4[zb + o] = hu;                                                  \
    }

    if (!rev) {
        for (int t = 0; t < TT; ++t) K3_STEP(t)
    } else {
        for (int t = TT - 1; t >= 0; --t) K3_STEP(t)
    }
#undef K3_STEP
}

// ---------- kernel 4: conv2+conv3 over bf16 h, double-buffered LDS (1 barrier/iter) ----------
// grid: (100 tiles 32x8, 4 t-chunks, 2 b), block 256
__global__ __launch_bounds__(256)
void k4_conv23(const unsigned short* __restrict__ hb, const float* __restrict__ wsc,
               const float* __restrict__ wsh, float* __restrict__ c2,
               float* __restrict__ c3, float* __restrict__ stats2) {
    __shared__ float pl[2][2][10*LSK];      // [buf][conv][10 rows x 40]
    __shared__ float red[4][4];

    int b  = blockIdx.z;
    int t0 = blockIdx.y * TCH;
    int t1 = min(t0 + TCH - 1, TT - 1);
    int tile = blockIdx.x;
    int ty0 = (tile / 5) * 8, tx0 = (tile % 5) * 32;
    int tid = threadIdx.x;
    int lyk = tid >> 5, lxk = tid & 31;
    int y = ty0 + lyk, x = tx0 + lxk;

    int ts = max(t0 - 1, 0), te = min(t1 + 1, TT - 1);
    int nplanes = (te - ts + 1) * 8;

    int i1 = tid + 256;
    int py0 = tid / 34, px0 = tid - py0*34;
    int py1 = i1 / 34, px1 = i1 - py1*34;
    int gy0 = ty0 - 1 + py0, gx0 = tx0 - 1 + px0;
    int gy1 = ty0 - 1 + py1, gx1 = tx0 - 1 + px1;
    bool ok0 = (gy0 >= 0 && gy0 < TH && gx0 >= 0 && gx0 < TW);
    bool ok1 = (i1 < 340) && (gy1 >= 0 && gy1 < TH && gx1 >= 0 && gx1 < TW);
    long off0 = (long)gy0*TW + gx0, off1 = (long)gy1*TW + gx1;
    int l0 = py0*LSK + px0, l1 = py1*LSK + px1;

    float accP2 = 0.f, accC2 = 0.f, accN2 = 0.f;
    float accP3 = 0.f, accC3 = 0.f, accN3 = 0.f;
    float s2l = 0.f, q2l = 0.f, s3l = 0.f, q3l = 0.f;

    unsigned short r2a, r2b, r3a, r3b;
    {
        long b2o = ((long)((b*HCN + 0)*TT + ts)) * THW;
        long b3o = ((long)((b*HCN + 8)*TT + ts)) * THW;
        r2a = ok0 ? hb[b2o + off0] : 0;
        r2b = ok1 ? hb[b2o + off1] : 0;
        r3a = ok0 ? hb[b3o + off0] : 0;
        r3b = ok1 ? hb[b3o + off1] : 0;
    }

    for (int p = 0; p < nplanes; ++p) {
        int buf = p & 1;
        int c = p & 7, t_in = ts + (p >> 3);

        pl[buf][0][l0] = b2f(r2a);
        pl[buf][1][l0] = b2f(r3a);
        if (i1 < 340) { pl[buf][0][l1] = b2f(r2b); pl[buf][1][l1] = b2f(r3b); }

        if (p + 1 < nplanes) {
            int cn = (p + 1) & 7, tn = ts + ((p + 1) >> 3);
            long b2o = ((long)((b*HCN + cn)*TT + tn)) * THW;
            long b3o = ((long)((b*HCN + 8 + cn)*TT + tn)) * THW;
            r2a = ok0 ? hb[b2o + off0] : 0;
            r2b = ok1 ? hb[b2o + off1] : 0;
            r3a = ok0 ? hb[b3o + off0] : 0;
            r3b = ok1 ? hb[b3o + off1] : 0;
        }
        __syncthreads();

        float t2[9], t3[9];
        #pragma unroll
        for (int ky = 0; ky < 3; ++ky)
            #pragma unroll
            for (int kx = 0; kx < 3; ++kx) {
                int li = (lyk + ky)*LSK + (lxk + kx);
                t2[ky*3 + kx] = pl[buf][0][li];
                t3[ky*3 + kx] = pl[buf][1][li];
            }
        const float* w2 = wsc + c*27;
        const float* w3 = wsh + c*27;
        #pragma unroll
        for (int i = 0; i < 9; ++i) {
            accN2 = fmaf(w2[i],      t2[i], accN2);
            accC2 = fmaf(w2[9 + i],  t2[i], accC2);
            accP2 = fmaf(w2[18 + i], t2[i], accP2);
            accN3 = fmaf(w3[i],      t3[i], accN3);
            accC3 = fmaf(w3[9 + i],  t3[i], accC3);
            accP3 = fmaf(w3[18 + i], t3[i], accP3);
        }

        if (c == 7) {
            int t_out = t_in - 1;
            if (t_out >= t0 && t_out <= t1) {
                long oidx = ((long)(b*TT + t_out)) * THW + (long)y*TW + x;
                c2[oidx] = accP2; c3[oidx] = accP3;
                s2l += accP2; q2l += accP2*accP2;
                s3l += accP3; q3l += accP3*accP3;
            }
            accP2 = accC2; accC2 = accN2; accN2 = 0.f;
            accP3 = accC3; accC3 = accN3; accN3 = 0.f;
        }
    }
    if (t1 == TT - 1) {
        long oidx = ((long)(b*TT + (TT - 1))) * THW + (long)y*TW + x;
        c2[oidx] = accP2; c3[oidx] = accP3;
        s2l += accP2; q2l += accP2*accP2;
        s3l += accP3; q3l += accP3*accP3;
    }

    #pragma unroll
    for (int off = 32; off > 0; off >>= 1) {
        s2l += __shfl_down(s2l, off, 64);
        q2l += __shfl_down(q2l, off, 64);
        s3l += __shfl_down(s3l, off, 64);
        q3l += __shfl_down(q3l, off, 64);
    }
    int lane = tid & 63, wid = tid >> 6;
    __syncthreads();
    if (lane == 0) { red[0][wid] = s2l; red[1][wid] = q2l; red[2][wid] = s3l; red[3][wid] = q3l; }
    __syncthreads();
    if (tid == 0) {
        #pragma unroll
        for (int j = 0; j < 4; ++j)
            atomicAdd(&stats2[j], red[j][0] + red[j][1] + red[j][2] + red[j][3]);
    }
}

// ---------- kernel 5: finalize scale/shift BN params ----------
__global__ void k5_fin2(const float* __restrict__ stats2,
                        const float* __restrict__ gs, const float* __restrict__ bs,
                        const float* __restrict__ gt, const float* __restrict__ bt,
                        float* __restrict__ ab2) {
    if (threadIdx.x == 0) {
        float n = (float)NPER;
        float m2 = stats2[0] / n, v2 = stats2[1] / n - m2*m2;
        float a2 = gs[0] * rsqrtf(v2 + 1e-5f);
        ab2[0] = a2; ab2[1] = bs[0] - m2*a2;
        float m3 = stats2[2] / n, v3 = stats2[3] / n - m3*m3;
        float a3 = gt[0] * rsqrtf(v3 + 1e-5f);
        ab2[2] = a3; ab2[3] = bt[0] - m3*a3;
    }
}

// ---------- kernel 6: epilogue, float4 ----------
__global__ __launch_bounds__(256)
void k6_final(const float4* __restrict__ c2, const float4* __restrict__ c3,
              const float* __restrict__ ab2, float4* __restrict__ out) {
    int i = blockIdx.x * blockDim.x + threadIdx.x;
    if (i < NPER/4) {
        float a2 = ab2[0], b2 = ab2[1], a3 = ab2[2], b3 = ab2[3];
        float4 v2 = c2[i], v3 = c3[i];
        float4 sc, sh;
        sc.x = sigmoidf_(fmaf(a2, v2.x, b2) + 2.f) + 1e-4f;
        sc.y = sigmoidf_(fmaf(a2, v2.y, b2) + 2.f) + 1e-4f;
        sc.z = sigmoidf_(fmaf(a2, v2.z, b2) + 2.f) + 1e-4f;
        sc.w = sigmoidf_(fmaf(a2, v2.w, b2) + 2.f) + 1e-4f;
        sh.x = fmaf(a3, v3.x, b3);
        sh.y = fmaf(a3, v3.y, b3);
        sh.z = fmaf(a3, v3.z, b3);
        sh.w = fmaf(a3, v3.w, b3);
        out[i] = sc;
        out[NPER/4 + i] = sh;
    }
}

// ---------- launch ----------
extern "C" void kernel_launch(void* const* d_in, const int* in_sizes, int n_in,
                              void* d_out, int out_size, void* d_ws, size_t ws_size,
                              hipStream_t stream) {
    const float* in          = (const float*)d_in[0];
    const float* w_gate      = (const float*)d_in[1];
    const float* gamma_gate  = (const float*)d_in[2];
    const float* beta_gate   = (const float*)d_in[3];
    const float* w_scale     = (const float*)d_in[4];
    const float* gamma_scale = (const float*)d_in[5];
    const float* beta_scale  = (const float*)d_in[6];
    const float* w_shift     = (const float*)d_in[7];
    const float* gamma_shift = (const float*)d_in[8];
    const float* beta_shift  = (const float*)d_in[9];
    const int*   rev         = (const int*)d_in[10];

    unsigned short* g   = (unsigned short*)d_ws;                    // gates bf16 (z then f); z-half becomes h
    float* c2  = (float*)((char*)d_ws + C2_BYTE);                   // aliases dead f-gates
    float* c3  = c2 + NPER;
    float* st  = (float*)((char*)d_ws + STATS_BYTE);
    float* s1  = st;            // 64
    float* ab1 = st + 64;       // 64
    float* s2  = st + 128;      // 4
    float* ab2 = st + 132;      // 4
    float* out = (float*)d_out;

    hipMemsetAsync(st, 0, 136 * sizeof(float), stream);

    k1_gates_stats<<<dim3(8, 100, TB), 256, 0, stream>>>(in, w_gate, g, s1);
    k2_fin1<<<1, 32, 0, stream>>>(s1, gamma_gate, beta_gate, ab1);
    k3_scan<<<dim3(25, HCN, TB), 256, 0, stream>>>(g, ab1, rev);
    k4_conv23<<<dim3(100, 4, TB), 256, 0, stream>>>(g, w_scale, w_shift, c2, c3, s2);
    k5_fin2<<<1, 64, 0, stream>>>(s2, gamma_scale, beta_scale, gamma_shift, beta_shift, ab2);
    k6_final<<<(NPER/4 + 255)/256, 256, 0, stream>>>((const float4*)c2, (const float4*)c3, ab2, (float4*)out);
}